// Round 5
// baseline (3694.744 us; speedup 1.0000x reference)
//
#include <hip/hip_runtime.h>

#define HH 51
#define HP 52     // padded hidden (multiple of 4)
#define NCH 13    // HP/4 float4 chunks

typedef float float4v __attribute__((ext_vector_type(4)));

__device__ __forceinline__ float sigmoid_f(float x) {
    return 1.0f / (1.0f + __expf(-x));
}
__device__ __forceinline__ float tanh_f(float x) {
    // 1 - 2/(e^{2x}+1); inf-safe at both ends
    return 1.0f - 2.0f / (__expf(2.0f * x) + 1.0f);
}

// 3 waves per block, 1 batch element per block.
// wave0: layer-1 GRU (W_hh1 rows in VGPRs), produces h1(t)
// wave1: gi2(t) = W_ih2 @ h1(t) + b_ih2   (lags 1 step)
// wave2: gh2 = W_hh2 @ h2 + fusion -> h2(t), out(t) (lags 2 steps)
//
// Gate semantics (PyTorch GRUCell, gates ordered r,z,n):
//   r = sig(i_r + h_r); z = sig(i_z + h_z); n = tanh(i_n + r*h_n)
//   where i_* includes b_ih and h_* includes b_hh.  b_hh_n must stay
//   INSIDE the r-multiplied term -> seed the n-accumulator with b_hh_n
//   and keep b_ih_n separate (folded into the i-side constant).
__global__ __launch_bounds__(192, 2)
void gru_seq_kernel(const float* __restrict__ input,
                    const float* __restrict__ w_ih1,
                    const float* __restrict__ w_hh1,
                    const float* __restrict__ b_ih1,
                    const float* __restrict__ b_hh1,
                    const float* __restrict__ w_ih2,
                    const float* __restrict__ w_hh2,
                    const float* __restrict__ b_ih2,
                    const float* __restrict__ b_hh2,
                    const float* __restrict__ lin_w,
                    const float* __restrict__ lin_b,
                    float* __restrict__ out,
                    int T)
{
    __shared__ __attribute__((aligned(16))) float h1buf[2][HP];
    __shared__ __attribute__((aligned(16))) float gi2buf[2][3][HP];
    __shared__ __attribute__((aligned(16))) float h2buf[2][HP];

    const int tid  = threadIdx.x;
    const int wave = tid >> 6;
    const int lane = tid & 63;
    const bool act = lane < HH;
    const int li   = act ? lane : 0;           // clamp for safe indexing
    const long long b  = blockIdx.x;
    const long long bT = b * (long long)T;

    // zero LDS (pad slots stay zero forever -> safe float4 dots)
    if (tid < HP) {
        h1buf[0][tid] = 0.f; h1buf[1][tid] = 0.f;
        h2buf[0][tid] = 0.f; h2buf[1][tid] = 0.f;
    }
    if (tid < 3 * HP) {
        ((float*)gi2buf)[tid]          = 0.f;
        ((float*)gi2buf)[3 * HP + tid] = 0.f;
    }

    // per-role weight matrix, rows (li, li+51, li+102) held in VGPRs
    const float* wsrc = (wave == 0) ? w_hh1 : ((wave == 1) ? w_ih2 : w_hh2);

    float4v wA[NCH], wB[NCH], wC[NCH];
    #pragma unroll
    for (int c = 0; c < NCH; ++c) {
        #pragma unroll
        for (int j = 0; j < 4; ++j) {
            const int k = 4 * c + j;
            float vA = 0.f, vB = 0.f, vC = 0.f;
            if (act && k < HH) {
                vA = wsrc[(li         ) * HH + k];
                vB = wsrc[(li +    HH ) * HH + k];
                vC = wsrc[(li + 2 * HH) * HH + k];
            }
            wA[c][j] = vA; wB[c][j] = vB; wC[c][j] = vC;
        }
    }

    // Accumulator seeds (h-side): r,z gates fold BOTH biases;
    // n gate seeds ONLY b_hh_n (it must be multiplied by r).
    float sA = 0.f, sB = 0.f, sC = 0.f;   // seeds for aA,aB,aC
    float tA = 0.f, tB = 0.f, tC = 0.f;   // x-weights (wave0) / lin (wave2)
    float uC = 0.f;                        // i-side n-gate bias (outside r)
    if (wave == 0) {
        if (act) {
            sA = b_hh1[li]          + b_ih1[li];            // r: fold both
            sB = b_hh1[li + HH]     + b_ih1[li + HH];       // z: fold both
            sC = b_hh1[li + 2 * HH];                        // n: h-side only
            uC = b_ih1[li + 2 * HH];                        // n: i-side
            tA = w_ih1[li]; tB = w_ih1[li + HH]; tC = w_ih1[li + 2 * HH];
        }
    } else if (wave == 1) {
        // produces gi2 = W_ih2@h1 + b_ih2 (pure i-side, no r involvement)
        if (act) { sA = b_ih2[li]; sB = b_ih2[li + HH]; sC = b_ih2[li + 2 * HH]; }
    } else {
        // h-side of layer 2: seed with b_hh2 (n-gate b_hh2 stays inside r)
        if (act) { sA = b_hh2[li]; sB = b_hh2[li + HH]; sC = b_hh2[li + 2 * HH]; tA = lin_w[li]; }
        tB = lin_b[0];
    }

    float hreg = 0.f;                        // wave0: h1[li]; wave2: h2[li]
    float4v xbuf = {0,0,0,0}, xnext = {0,0,0,0};
    if (wave == 0) xbuf = *(const float4v*)(input + bT);   // bT % 4 == 0

    __syncthreads();

    for (int i = 0; i <= T + 1; ++i) {
        const int wr_p = i & 1;
        const int rd_p = (i + 1) & 1;        // == (i-1)&1

        if (wave == 0) {
            if (i < T) {
                if ((i & 3) == 0 && (i + 4) < T)
                    xnext = *(const float4v*)(input + bT + i + 4);
                const float xc = (i & 2) ? ((i & 1) ? xbuf[3] : xbuf[2])
                                         : ((i & 1) ? xbuf[1] : xbuf[0]);
                const float4v* hb = (const float4v*)h1buf[rd_p];
                float4v aA = {sA, 0.f, 0.f, 0.f};
                float4v aB = {sB, 0.f, 0.f, 0.f};
                float4v aC = {sC, 0.f, 0.f, 0.f};
                #pragma unroll
                for (int c = 0; c < NCH; ++c) {
                    const float4v h4 = hb[c];
                    aA += wA[c] * h4; aB += wB[c] * h4; aC += wC[c] * h4;
                }
                const float hr = (aA[0]+aA[1]) + (aA[2]+aA[3]);   // W_hh_r@h + b_r
                const float hz = (aB[0]+aB[1]) + (aB[2]+aB[3]);
                const float hn = (aC[0]+aC[1]) + (aC[2]+aC[3]);   // W_hh_n@h + b_hh_n
                const float r  = sigmoid_f(__fmaf_rn(xc, tA, hr));
                const float z  = sigmoid_f(__fmaf_rn(xc, tB, hz));
                const float in_ = __fmaf_rn(xc, tC, uC);          // i_n
                const float nn = tanh_f(__fmaf_rn(r, hn, in_));
                hreg = __fmaf_rn(z, hreg - nn, nn);               // (1-z)n + z h
                if (act) h1buf[wr_p][li] = hreg;
                if ((i & 3) == 3) xbuf = xnext;
            }
        } else if (wave == 1) {
            if (i >= 1 && i <= T) {
                const float4v* hb = (const float4v*)h1buf[rd_p];   // h1(i-1)
                float4v aA = {sA, 0.f, 0.f, 0.f};
                float4v aB = {sB, 0.f, 0.f, 0.f};
                float4v aC = {sC, 0.f, 0.f, 0.f};
                #pragma unroll
                for (int c = 0; c < NCH; ++c) {
                    const float4v h4 = hb[c];
                    aA += wA[c] * h4; aB += wB[c] * h4; aC += wC[c] * h4;
                }
                if (act) {
                    gi2buf[wr_p][0][li] = (aA[0]+aA[1]) + (aA[2]+aA[3]);
                    gi2buf[wr_p][1][li] = (aB[0]+aB[1]) + (aB[2]+aB[3]);
                    gi2buf[wr_p][2][li] = (aC[0]+aC[1]) + (aC[2]+aC[3]);
                }
            }
        } else {
            if (i >= 2) {
                const float4v* hb = (const float4v*)h2buf[rd_p];   // h2(i-3)
                float4v aA = {sA, 0.f, 0.f, 0.f};
                float4v aB = {sB, 0.f, 0.f, 0.f};
                float4v aC = {sC, 0.f, 0.f, 0.f};
                #pragma unroll
                for (int c = 0; c < NCH; ++c) {
                    const float4v h4 = hb[c];
                    aA += wA[c] * h4; aB += wB[c] * h4; aC += wC[c] * h4;
                }
                const float hr = (aA[0]+aA[1]) + (aA[2]+aA[3]);   // + b_hh2_r
                const float hz = (aB[0]+aB[1]) + (aB[2]+aB[3]);
                const float hn = (aC[0]+aC[1]) + (aC[2]+aC[3]);   // + b_hh2_n
                const float gr = gi2buf[rd_p][0][li];       // gi2(i-2) incl b_ih2
                const float gz = gi2buf[rd_p][1][li];
                const float gn = gi2buf[rd_p][2][li];
                const float r  = sigmoid_f(gr + hr);
                const float z  = sigmoid_f(gz + hz);
                const float nn = tanh_f(__fmaf_rn(r, hn, gn));
                hreg = __fmaf_rn(z, hreg - nn, nn);
                if (act) h2buf[wr_p][li] = hreg;
                float red = act ? tA * hreg : 0.f;
                #pragma unroll
                for (int m = 32; m >= 1; m >>= 1) red += __shfl_xor(red, m);
                if (lane == 0) out[bT + (i - 2)] = red + tB;
            }
        }
        __syncthreads();
    }
}

extern "C" void kernel_launch(void* const* d_in, const int* in_sizes, int n_in,
                              void* d_out, int out_size, void* d_ws, size_t ws_size,
                              hipStream_t stream) {
    const float* input = (const float*)d_in[0];
    const float* w_ih1 = (const float*)d_in[1];
    const float* w_hh1 = (const float*)d_in[2];
    const float* b_ih1 = (const float*)d_in[3];
    const float* b_hh1 = (const float*)d_in[4];
    const float* w_ih2 = (const float*)d_in[5];
    const float* w_hh2 = (const float*)d_in[6];
    const float* b_ih2 = (const float*)d_in[7];
    const float* b_hh2 = (const float*)d_in[8];
    const float* lin_w = (const float*)d_in[9];
    const float* lin_b = (const float*)d_in[10];

    const int B = 2048;
    const int T = in_sizes[0] / B;   // 1024

    float* out = (float*)d_out;
    gru_seq_kernel<<<B, 192, 0, stream>>>(input, w_ih1, w_hh1, b_ih1, b_hh1,
                                          w_ih2, w_hh2, b_ih2, b_hh2,
                                          lin_w, lin_b, out, T);
}

// Round 9
// 2753.713 us; speedup vs baseline: 1.3417x; 1.3417x over previous
//
#include <hip/hip_runtime.h>

#define HH 51
#define HP 52     // padded hidden (multiple of 4)
#define NCH 13    // HP/4 float4 chunks
#define HIST_D 64     // h2 history ring depth (timesteps)
#define HIST_W 107    // ring row stride in floats (odd -> conflict-free); elem e at col e*53
#define BURST 32      // output-head batch size (timesteps per burst)

typedef float float4v __attribute__((ext_vector_type(4)));

__device__ __forceinline__ float sigmoid_f(float x) {
    return 1.0f / (1.0f + __expf(-x));
}
__device__ __forceinline__ float tanh_f(float x) {
    // 1 - 2/(e^{2x}+1); inf-safe at both ends
    return 1.0f - 2.0f / (__expf(2.0f * x) + 1.0f);
}

// select element k (runtime 0..3) from a float4 without dynamic vector indexing
__device__ __forceinline__ float sel4(const float4v v, int k) {
    const float a = (k & 1) ? v[1] : v[0];
    const float b = (k & 1) ? v[3] : v[2];
    return (k & 2) ? b : a;
}

// 4 waves per block (multiple of 4 -> no idle SIMD slot), TWO batch elems/block.
// wave0: layer-1 GRU (W_hh1 in regs) -> h1(t) for e0,e1           [iters 0..T-1]
// wave1: gi2(t) = W_ih2 @ h1(t) + b_ih2, lag 1                    [iters 1..T]
// wave2: L2 h-dot + gate fusion -> h2(t), lag 2; writes h2 ring   [iters 2..T+1]
// wave3: output head in bursts of 32 steps x 2 elems from h2 ring [every 32 iters]
//
// PyTorch GRUCell gates (r,z,n): r=sig(i_r+h_r); z=sig(i_z+h_z); n=tanh(i_n + r*h_n).
// b_hh_n stays INSIDE the r-multiplied term (seed n-acc with b_hh_n only);
// b_ih_n stays outside (uC). r/z gates fold both biases.
__global__ __launch_bounds__(256, 2)
void gru_seq_kernel(const float* __restrict__ input,
                    const float* __restrict__ w_ih1,
                    const float* __restrict__ w_hh1,
                    const float* __restrict__ b_ih1,
                    const float* __restrict__ b_hh1,
                    const float* __restrict__ w_ih2,
                    const float* __restrict__ w_hh2,
                    const float* __restrict__ b_ih2,
                    const float* __restrict__ b_hh2,
                    const float* __restrict__ lin_w,
                    const float* __restrict__ lin_b,
                    float* __restrict__ out,
                    int T)
{
    __shared__ __attribute__((aligned(16))) float h1buf[2][2][HP];      // [parity][elem][unit]
    __shared__ __attribute__((aligned(16))) float gi2buf[2][3][2][HP];  // [parity][gate][elem][unit]
    __shared__ __attribute__((aligned(16))) float h2buf[2][2][HP];
    __shared__ __attribute__((aligned(16))) float h2hist[HIST_D][HIST_W];
    __shared__ __attribute__((aligned(16))) float lwbuf[HP];

    const int tid  = threadIdx.x;
    const int wave = tid >> 6;
    const int lane = tid & 63;
    const bool act = lane < HH;
    const int li   = act ? lane : 0;
    const long long bT0 = 2LL * blockIdx.x * T;
    const long long bT1 = bT0 + T;

    // zero the double-buffers (pad slots stay zero forever -> safe float4 dots)
    for (int s = tid; s < 2 * 2 * HP; s += 256) {
        ((float*)h1buf)[s] = 0.f;
        ((float*)h2buf)[s] = 0.f;
    }
    for (int s = tid; s < 2 * 3 * 2 * HP; s += 256) ((float*)gi2buf)[s] = 0.f;
    if (tid < HP) lwbuf[tid] = (tid < HH) ? lin_w[tid] : 0.f;
    // h2hist needs no init: every slot is written (iter t+2) before read (iter >= t+3)

    // per-role weight matrix, rows (li, li+51, li+102) held in registers
    const float* wsrc = (wave == 0) ? w_hh1 : ((wave == 1) ? w_ih2 : w_hh2);

    float4v wA[NCH], wB[NCH], wC[NCH];
    #pragma unroll
    for (int c = 0; c < NCH; ++c) {
        #pragma unroll
        for (int j = 0; j < 4; ++j) {
            const int k = 4 * c + j;
            float vA = 0.f, vB = 0.f, vC = 0.f;
            if (wave < 3 && act && k < HH) {
                vA = wsrc[(li         ) * HH + k];
                vB = wsrc[(li +    HH ) * HH + k];
                vC = wsrc[(li + 2 * HH) * HH + k];
            }
            wA[c][j] = vA; wB[c][j] = vB; wC[c][j] = vC;
        }
    }

    // role scalars
    float sA = 0.f, sB = 0.f, sC = 0.f;   // accumulator seeds (h-side biases)
    float tA = 0.f, tB = 0.f, tC = 0.f;   // wave0: x-weights; wave3: tB = lin_b
    float uC = 0.f;                        // wave0: i-side n-gate bias
    if (wave == 0) {
        if (act) {
            sA = b_hh1[li]          + b_ih1[li];        // r: fold both biases
            sB = b_hh1[li + HH]     + b_ih1[li + HH];   // z: fold both
            sC = b_hh1[li + 2 * HH];                    // n: h-side only (inside r)
            uC = b_ih1[li + 2 * HH];                    // n: i-side (outside r)
            tA = w_ih1[li]; tB = w_ih1[li + HH]; tC = w_ih1[li + 2 * HH];
        }
    } else if (wave == 1) {
        if (act) { sA = b_ih2[li]; sB = b_ih2[li + HH]; sC = b_ih2[li + 2 * HH]; }
    } else if (wave == 2) {
        if (act) { sA = b_hh2[li]; sB = b_hh2[li + HH]; sC = b_hh2[li + 2 * HH]; }
    } else {
        tB = lin_b[0];
    }

    float hr0 = 0.f, hr1 = 0.f;            // wave0: h1[li] e0/e1; wave2: h2[li] e0/e1
    float4v xb0 = {0,0,0,0}, xb1 = {0,0,0,0}, xn0 = {0,0,0,0}, xn1 = {0,0,0,0};
    if (wave == 0) {
        xb0 = *(const float4v*)(input + bT0);   // bT % 4 == 0 (T multiple of 4)
        xb1 = *(const float4v*)(input + bT1);
    }

    __syncthreads();

    for (int i = 0; i <= T + 2; ++i) {
        const int wr = i & 1;
        const int rd = (i + 1) & 1;        // previous parity

        if (wave == 0) {
            if (i < T) {
                if ((i & 3) == 0 && i + 4 < T) {
                    xn0 = *(const float4v*)(input + bT0 + i + 4);
                    xn1 = *(const float4v*)(input + bT1 + i + 4);
                }
                const float xc0 = sel4(xb0, i & 3);
                const float xc1 = sel4(xb1, i & 3);
                const float4v* hb0 = (const float4v*)h1buf[rd][0];
                const float4v* hb1 = (const float4v*)h1buf[rd][1];
                float4v aA0 = {sA,0.f,0.f,0.f}, aB0 = {sB,0.f,0.f,0.f}, aC0 = {sC,0.f,0.f,0.f};
                float4v aA1 = {sA,0.f,0.f,0.f}, aB1 = {sB,0.f,0.f,0.f}, aC1 = {sC,0.f,0.f,0.f};
                #pragma unroll
                for (int c = 0; c < NCH; ++c) {
                    const float4v h40 = hb0[c], h41 = hb1[c];
                    aA0 += wA[c] * h40; aB0 += wB[c] * h40; aC0 += wC[c] * h40;
                    aA1 += wA[c] * h41; aB1 += wB[c] * h41; aC1 += wC[c] * h41;
                }
                const float hA0 = (aA0[0]+aA0[1]) + (aA0[2]+aA0[3]);
                const float hB0 = (aB0[0]+aB0[1]) + (aB0[2]+aB0[3]);
                const float hC0 = (aC0[0]+aC0[1]) + (aC0[2]+aC0[3]);
                const float hA1 = (aA1[0]+aA1[1]) + (aA1[2]+aA1[3]);
                const float hB1 = (aB1[0]+aB1[1]) + (aB1[2]+aB1[3]);
                const float hC1 = (aC1[0]+aC1[1]) + (aC1[2]+aC1[3]);
                const float r0 = sigmoid_f(__fmaf_rn(xc0, tA, hA0));
                const float r1 = sigmoid_f(__fmaf_rn(xc1, tA, hA1));
                const float z0 = sigmoid_f(__fmaf_rn(xc0, tB, hB0));
                const float z1 = sigmoid_f(__fmaf_rn(xc1, tB, hB1));
                const float n0 = tanh_f(__fmaf_rn(r0, hC0, __fmaf_rn(xc0, tC, uC)));
                const float n1 = tanh_f(__fmaf_rn(r1, hC1, __fmaf_rn(xc1, tC, uC)));
                hr0 = __fmaf_rn(z0, hr0 - n0, n0);   // (1-z)n + z h
                hr1 = __fmaf_rn(z1, hr1 - n1, n1);
                if (act) { h1buf[wr][0][li] = hr0; h1buf[wr][1][li] = hr1; }
                if ((i & 3) == 3) { xb0 = xn0; xb1 = xn1; }
            }
        } else if (wave == 1) {
            if (i >= 1 && i <= T) {
                const float4v* hb0 = (const float4v*)h1buf[rd][0];   // h1(i-1)
                const float4v* hb1 = (const float4v*)h1buf[rd][1];
                float4v aA0 = {sA,0.f,0.f,0.f}, aB0 = {sB,0.f,0.f,0.f}, aC0 = {sC,0.f,0.f,0.f};
                float4v aA1 = {sA,0.f,0.f,0.f}, aB1 = {sB,0.f,0.f,0.f}, aC1 = {sC,0.f,0.f,0.f};
                #pragma unroll
                for (int c = 0; c < NCH; ++c) {
                    const float4v h40 = hb0[c], h41 = hb1[c];
                    aA0 += wA[c] * h40; aB0 += wB[c] * h40; aC0 += wC[c] * h40;
                    aA1 += wA[c] * h41; aB1 += wB[c] * h41; aC1 += wC[c] * h41;
                }
                if (act) {
                    gi2buf[wr][0][0][li] = (aA0[0]+aA0[1]) + (aA0[2]+aA0[3]);
                    gi2buf[wr][1][0][li] = (aB0[0]+aB0[1]) + (aB0[2]+aB0[3]);
                    gi2buf[wr][2][0][li] = (aC0[0]+aC0[1]) + (aC0[2]+aC0[3]);
                    gi2buf[wr][0][1][li] = (aA1[0]+aA1[1]) + (aA1[2]+aA1[3]);
                    gi2buf[wr][1][1][li] = (aB1[0]+aB1[1]) + (aB1[2]+aB1[3]);
                    gi2buf[wr][2][1][li] = (aC1[0]+aC1[1]) + (aC1[2]+aC1[3]);
                }
            }
        } else if (wave == 2) {
            if (i >= 2 && i <= T + 1) {
                const float4v* hb0 = (const float4v*)h2buf[rd][0];   // h2(i-3)
                const float4v* hb1 = (const float4v*)h2buf[rd][1];
                float4v aA0 = {sA,0.f,0.f,0.f}, aB0 = {sB,0.f,0.f,0.f}, aC0 = {sC,0.f,0.f,0.f};
                float4v aA1 = {sA,0.f,0.f,0.f}, aB1 = {sB,0.f,0.f,0.f}, aC1 = {sC,0.f,0.f,0.f};
                #pragma unroll
                for (int c = 0; c < NCH; ++c) {
                    const float4v h40 = hb0[c], h41 = hb1[c];
                    aA0 += wA[c] * h40; aB0 += wB[c] * h40; aC0 += wC[c] * h40;
                    aA1 += wA[c] * h41; aB1 += wB[c] * h41; aC1 += wC[c] * h41;
                }
                const float hA0 = (aA0[0]+aA0[1]) + (aA0[2]+aA0[3]);   // + b_hh2_r
                const float hB0 = (aB0[0]+aB0[1]) + (aB0[2]+aB0[3]);
                const float hC0 = (aC0[0]+aC0[1]) + (aC0[2]+aC0[3]);   // + b_hh2_n
                const float hA1 = (aA1[0]+aA1[1]) + (aA1[2]+aA1[3]);
                const float hB1 = (aB1[0]+aB1[1]) + (aB1[2]+aB1[3]);
                const float hC1 = (aC1[0]+aC1[1]) + (aC1[2]+aC1[3]);
                const float r0 = sigmoid_f(gi2buf[rd][0][0][li] + hA0);   // gi2(i-2)
                const float r1 = sigmoid_f(gi2buf[rd][0][1][li] + hA1);
                const float z0 = sigmoid_f(gi2buf[rd][1][0][li] + hB0);
                const float z1 = sigmoid_f(gi2buf[rd][1][1][li] + hB1);
                const float n0 = tanh_f(__fmaf_rn(r0, hC0, gi2buf[rd][2][0][li]));
                const float n1 = tanh_f(__fmaf_rn(r1, hC1, gi2buf[rd][2][1][li]));
                hr0 = __fmaf_rn(z0, hr0 - n0, n0);
                hr1 = __fmaf_rn(z1, hr1 - n1, n1);
                const int slot = (i - 2) & (HIST_D - 1);
                if (act) {
                    h2buf[wr][0][li] = hr0; h2buf[wr][1][li] = hr1;
                    h2hist[slot][li] = hr0; h2hist[slot][53 + li] = hr1;
                }
            }
        } else {
            // output head: every 32 iters, 32 steps x 2 elems; lane = e*32 + step
            if (i >= BURST + 2 && ((i - 2) & (BURST - 1)) == 0) {
                const int t0 = i - 2 - BURST;
                const int e  = lane >> 5;
                const int tt = t0 + (lane & 31);
                const int col = e * 53;
                float acc = tB;
                #pragma unroll
                for (int k = 0; k < HH; ++k)
                    acc = __fmaf_rn(lwbuf[k], h2hist[tt & (HIST_D - 1)][col + k], acc);
                out[(e ? bT1 : bT0) + tt] = acc;
            }
        }
        __syncthreads();
    }
}

extern "C" void kernel_launch(void* const* d_in, const int* in_sizes, int n_in,
                              void* d_out, int out_size, void* d_ws, size_t ws_size,
                              hipStream_t stream) {
    const float* input = (const float*)d_in[0];
    const float* w_ih1 = (const float*)d_in[1];
    const float* w_hh1 = (const float*)d_in[2];
    const float* b_ih1 = (const float*)d_in[3];
    const float* b_hh1 = (const float*)d_in[4];
    const float* w_ih2 = (const float*)d_in[5];
    const float* w_hh2 = (const float*)d_in[6];
    const float* b_ih2 = (const float*)d_in[7];
    const float* b_hh2 = (const float*)d_in[8];
    const float* lin_w = (const float*)d_in[9];
    const float* lin_b = (const float*)d_in[10];

    const int B = 2048;
    const int T = in_sizes[0] / B;   // 1024 (multiple of BURST and of 4)

    float* out = (float*)d_out;
    gru_seq_kernel<<<B / 2, 256, 0, stream>>>(input, w_ih1, w_hh1, b_ih1, b_hh1,
                                              w_ih2, w_hh2, b_ih2, b_hh2,
                                              lin_w, lin_b, out, T);
}

// Round 10
// 2264.104 us; speedup vs baseline: 1.6319x; 1.2162x over previous
//
#include <hip/hip_runtime.h>

#define HH 51
#define HP 52         // padded hidden for f32 gi2 rows
#define NH2 28        // half2 chunks per weight row (56 halves, pad 0)
#define NU4 7         // uint4 (8-half) LDS reads per h row
#define HIST_D 64     // h2 history ring depth (timesteps)
#define HIST_W 107    // ring row stride floats (bank step 11, coprime 32)
#define BURST 32      // output-head batch size

typedef float  float4v __attribute__((ext_vector_type(4)));
typedef unsigned int uint4v __attribute__((ext_vector_type(4)));
typedef _Float16 half2v __attribute__((ext_vector_type(2)));

__device__ __forceinline__ float sigmoid_f(float x) {
    return 1.0f / (1.0f + __expf(-x));
}
__device__ __forceinline__ float tanh_f(float x) {
    return 1.0f - 2.0f / (__expf(2.0f * x) + 1.0f);   // inf-safe
}
__device__ __forceinline__ float sel4(const float4v v, int k) {
    const float a = (k & 1) ? v[1] : v[0];
    const float b = (k & 1) ? v[3] : v[2];
    return (k & 2) ? b : a;
}
// f16 pair dot with f32 accumulate; exact-math fallback if builtin missing
__device__ __forceinline__ float qdot(half2v w, half2v h, float acc) {
#if __has_builtin(__builtin_amdgcn_fdot2)
    return __builtin_amdgcn_fdot2(w, h, acc, false);
#else
    return fmaf((float)w[0], (float)h[0], fmaf((float)w[1], (float)h[1], acc));
#endif
}

// 4 waves/block, TWO batch elems/block. Same pipeline as v2' but the W·h dots
// run on v_dot2_f32_f16 (f16 weights + f16 h broadcast, f32 accumulate).
// wave0: layer-1 GRU -> h1(t) [f32 state, writes f16 h1]      [iters 0..T-1]
// wave1: gi2(t) = W_ih2@h1 + b_ih2 (f32 out), lag 1           [iters 1..T]
// wave2: W_hh2@h2 dot + fusion -> h2(t) (f16 + f32 ring), lag 2
// wave3: output head, 32-step bursts from f32 ring
//
// GRU gates (r,z,n): r=sig(i_r+h_r); z=sig(i_z+h_z); n=tanh(i_n + r*h_n).
// b_hh_n seeds the r-multiplied accumulator; b_ih_n stays outside.
__global__ __launch_bounds__(256, 2)
void gru_seq_kernel(const float* __restrict__ input,
                    const float* __restrict__ w_ih1,
                    const float* __restrict__ w_hh1,
                    const float* __restrict__ b_ih1,
                    const float* __restrict__ b_hh1,
                    const float* __restrict__ w_ih2,
                    const float* __restrict__ w_hh2,
                    const float* __restrict__ b_ih2,
                    const float* __restrict__ b_hh2,
                    const float* __restrict__ lin_w,
                    const float* __restrict__ lin_b,
                    float* __restrict__ out,
                    int T)
{
    __shared__ __attribute__((aligned(16))) unsigned int h1f16[2][2][NH2]; // f16 h1 broadcast
    __shared__ __attribute__((aligned(16))) unsigned int h2f16[2][2][NH2]; // f16 h2 broadcast
    __shared__ __attribute__((aligned(16))) float gi2buf[2][3][2][HP];     // f32 gi2
    __shared__ __attribute__((aligned(16))) float h2hist[HIST_D][HIST_W];  // f32 ring
    __shared__ __attribute__((aligned(16))) float lwbuf[HP];

    const int tid  = threadIdx.x;
    const int wave = tid >> 6;
    const int lane = tid & 63;
    const bool act = lane < HH;
    const int li   = act ? lane : 0;
    const long long bT0 = 2LL * blockIdx.x * T;
    const long long bT1 = bT0 + T;

    // zero broadcast buffers (pad halves stay zero -> safe 8-half dots)
    for (int s = tid; s < 2 * 2 * NH2; s += 256) {
        ((unsigned int*)h1f16)[s] = 0u;
        ((unsigned int*)h2f16)[s] = 0u;
    }
    for (int s = tid; s < 2 * 3 * 2 * HP; s += 256) ((float*)gi2buf)[s] = 0.f;
    if (tid < HP) lwbuf[tid] = (tid < HH) ? lin_w[tid] : 0.f;

    // per-role weight rows (li, li+51, li+102) quantized to f16 pairs (RTN)
    const float* wsrc = (wave == 0) ? w_hh1 : ((wave == 1) ? w_ih2 : w_hh2);
    half2v wA[NH2], wB[NH2], wC[NH2];
    #pragma unroll
    for (int c = 0; c < NH2; ++c) {
        const int k0 = 2 * c, k1 = 2 * c + 1;
        half2v a = {(_Float16)0.f, (_Float16)0.f};
        half2v b = a, d = a;
        if (wave < 3 && act) {
            if (k0 < HH) {
                a[0] = (_Float16)wsrc[(li         ) * HH + k0];
                b[0] = (_Float16)wsrc[(li +    HH ) * HH + k0];
                d[0] = (_Float16)wsrc[(li + 2 * HH) * HH + k0];
            }
            if (k1 < HH) {
                a[1] = (_Float16)wsrc[(li         ) * HH + k1];
                b[1] = (_Float16)wsrc[(li +    HH ) * HH + k1];
                d[1] = (_Float16)wsrc[(li + 2 * HH) * HH + k1];
            }
        }
        wA[c] = a; wB[c] = b; wC[c] = d;
    }

    // role scalars
    float sA = 0.f, sB = 0.f, sC = 0.f;   // accumulator seeds (h-side biases)
    float tA = 0.f, tB = 0.f, tC = 0.f;   // wave0: x-weights; wave3: tB = lin_b
    float uC = 0.f;                        // wave0: i-side n-gate bias
    if (wave == 0) {
        if (act) {
            sA = b_hh1[li]          + b_ih1[li];        // r: fold both biases
            sB = b_hh1[li + HH]     + b_ih1[li + HH];   // z: fold both
            sC = b_hh1[li + 2 * HH];                    // n: h-side only (inside r)
            uC = b_ih1[li + 2 * HH];                    // n: i-side (outside r)
            tA = w_ih1[li]; tB = w_ih1[li + HH]; tC = w_ih1[li + 2 * HH];
        }
    } else if (wave == 1) {
        if (act) { sA = b_ih2[li]; sB = b_ih2[li + HH]; sC = b_ih2[li + 2 * HH]; }
    } else if (wave == 2) {
        if (act) { sA = b_hh2[li]; sB = b_hh2[li + HH]; sC = b_hh2[li + 2 * HH]; }
    } else {
        tB = lin_b[0];
    }

    float hr0 = 0.f, hr1 = 0.f;
    float4v xb0 = {0,0,0,0}, xb1 = {0,0,0,0}, xn0 = {0,0,0,0}, xn1 = {0,0,0,0};
    if (wave == 0) {
        xb0 = *(const float4v*)(input + bT0);
        xb1 = *(const float4v*)(input + bT1);
    }

    __syncthreads();

    for (int i = 0; i <= T + 2; ++i) {
        const int wr = i & 1;
        const int rd = (i + 1) & 1;

        if (wave == 0) {
            if (i < T) {
                if ((i & 3) == 0 && i + 4 < T) {
                    xn0 = *(const float4v*)(input + bT0 + i + 4);
                    xn1 = *(const float4v*)(input + bT1 + i + 4);
                }
                const float xc0 = sel4(xb0, i & 3);
                const float xc1 = sel4(xb1, i & 3);
                const uint4v* hb0 = (const uint4v*)h1f16[rd][0];
                const uint4v* hb1 = (const uint4v*)h1f16[rd][1];
                float aA0 = sA, aB0 = sB, aC0 = sC;
                float aA1 = sA, aB1 = sB, aC1 = sC;
                #pragma unroll
                for (int cc = 0; cc < NU4; ++cc) {
                    const uint4v u0 = hb0[cc], u1 = hb1[cc];
                    #pragma unroll
                    for (int j = 0; j < 4; ++j) {
                        const int c = 4 * cc + j;
                        const half2v h0 = __builtin_bit_cast(half2v, (unsigned int)u0[j]);
                        const half2v h1 = __builtin_bit_cast(half2v, (unsigned int)u1[j]);
                        aA0 = qdot(wA[c], h0, aA0); aB0 = qdot(wB[c], h0, aB0); aC0 = qdot(wC[c], h0, aC0);
                        aA1 = qdot(wA[c], h1, aA1); aB1 = qdot(wB[c], h1, aB1); aC1 = qdot(wC[c], h1, aC1);
                    }
                }
                const float r0 = sigmoid_f(__fmaf_rn(xc0, tA, aA0));
                const float r1 = sigmoid_f(__fmaf_rn(xc1, tA, aA1));
                const float z0 = sigmoid_f(__fmaf_rn(xc0, tB, aB0));
                const float z1 = sigmoid_f(__fmaf_rn(xc1, tB, aB1));
                const float n0 = tanh_f(__fmaf_rn(r0, aC0, __fmaf_rn(xc0, tC, uC)));
                const float n1 = tanh_f(__fmaf_rn(r1, aC1, __fmaf_rn(xc1, tC, uC)));
                hr0 = __fmaf_rn(z0, hr0 - n0, n0);   // (1-z)n + z h
                hr1 = __fmaf_rn(z1, hr1 - n1, n1);
                if (act) {
                    ((_Float16*)h1f16[wr][0])[li] = (_Float16)hr0;
                    ((_Float16*)h1f16[wr][1])[li] = (_Float16)hr1;
                }
                if ((i & 3) == 3) { xb0 = xn0; xb1 = xn1; }
            }
        } else if (wave == 1) {
            if (i >= 1 && i <= T) {
                const uint4v* hb0 = (const uint4v*)h1f16[rd][0];   // h1(i-1)
                const uint4v* hb1 = (const uint4v*)h1f16[rd][1];
                float aA0 = sA, aB0 = sB, aC0 = sC;
                float aA1 = sA, aB1 = sB, aC1 = sC;
                #pragma unroll
                for (int cc = 0; cc < NU4; ++cc) {
                    const uint4v u0 = hb0[cc], u1 = hb1[cc];
                    #pragma unroll
                    for (int j = 0; j < 4; ++j) {
                        const int c = 4 * cc + j;
                        const half2v h0 = __builtin_bit_cast(half2v, (unsigned int)u0[j]);
                        const half2v h1 = __builtin_bit_cast(half2v, (unsigned int)u1[j]);
                        aA0 = qdot(wA[c], h0, aA0); aB0 = qdot(wB[c], h0, aB0); aC0 = qdot(wC[c], h0, aC0);
                        aA1 = qdot(wA[c], h1, aA1); aB1 = qdot(wB[c], h1, aB1); aC1 = qdot(wC[c], h1, aC1);
                    }
                }
                if (act) {
                    gi2buf[wr][0][0][li] = aA0; gi2buf[wr][0][1][li] = aA1;
                    gi2buf[wr][1][0][li] = aB0; gi2buf[wr][1][1][li] = aB1;
                    gi2buf[wr][2][0][li] = aC0; gi2buf[wr][2][1][li] = aC1;
                }
            }
        } else if (wave == 2) {
            if (i >= 2 && i <= T + 1) {
                const uint4v* hb0 = (const uint4v*)h2f16[rd][0];   // h2(i-3)
                const uint4v* hb1 = (const uint4v*)h2f16[rd][1];
                float aA0 = sA, aB0 = sB, aC0 = sC;
                float aA1 = sA, aB1 = sB, aC1 = sC;
                #pragma unroll
                for (int cc = 0; cc < NU4; ++cc) {
                    const uint4v u0 = hb0[cc], u1 = hb1[cc];
                    #pragma unroll
                    for (int j = 0; j < 4; ++j) {
                        const int c = 4 * cc + j;
                        const half2v h0 = __builtin_bit_cast(half2v, (unsigned int)u0[j]);
                        const half2v h1 = __builtin_bit_cast(half2v, (unsigned int)u1[j]);
                        aA0 = qdot(wA[c], h0, aA0); aB0 = qdot(wB[c], h0, aB0); aC0 = qdot(wC[c], h0, aC0);
                        aA1 = qdot(wA[c], h1, aA1); aB1 = qdot(wB[c], h1, aB1); aC1 = qdot(wC[c], h1, aC1);
                    }
                }
                const float r0 = sigmoid_f(gi2buf[rd][0][0][li] + aA0);   // gi2(i-2)
                const float r1 = sigmoid_f(gi2buf[rd][0][1][li] + aA1);
                const float z0 = sigmoid_f(gi2buf[rd][1][0][li] + aB0);
                const float z1 = sigmoid_f(gi2buf[rd][1][1][li] + aB1);
                const float n0 = tanh_f(__fmaf_rn(r0, aC0, gi2buf[rd][2][0][li]));
                const float n1 = tanh_f(__fmaf_rn(r1, aC1, gi2buf[rd][2][1][li]));
                hr0 = __fmaf_rn(z0, hr0 - n0, n0);
                hr1 = __fmaf_rn(z1, hr1 - n1, n1);
                const int slot = (i - 2) & (HIST_D - 1);
                if (act) {
                    ((_Float16*)h2f16[wr][0])[li] = (_Float16)hr0;
                    ((_Float16*)h2f16[wr][1])[li] = (_Float16)hr1;
                    h2hist[slot][li] = hr0; h2hist[slot][53 + li] = hr1;
                }
            }
        } else {
            // output head: every 32 iters, 32 steps x 2 elems; lane = e*32 + step
            if (i >= BURST + 2 && ((i - 2) & (BURST - 1)) == 0) {
                const int t0 = i - 2 - BURST;
                const int e  = lane >> 5;
                const int tt = t0 + (lane & 31);
                const int col = e * 53;
                float acc = tB;
                #pragma unroll
                for (int k = 0; k < HH; ++k)
                    acc = __fmaf_rn(lwbuf[k], h2hist[tt & (HIST_D - 1)][col + k], acc);
                out[(e ? bT1 : bT0) + tt] = acc;
            }
        }
        __syncthreads();
    }
}

extern "C" void kernel_launch(void* const* d_in, const int* in_sizes, int n_in,
                              void* d_out, int out_size, void* d_ws, size_t ws_size,
                              hipStream_t stream) {
    const float* input = (const float*)d_in[0];
    const float* w_ih1 = (const float*)d_in[1];
    const float* w_hh1 = (const float*)d_in[2];
    const float* b_ih1 = (const float*)d_in[3];
    const float* b_hh1 = (const float*)d_in[4];
    const float* w_ih2 = (const float*)d_in[5];
    const float* w_hh2 = (const float*)d_in[6];
    const float* b_ih2 = (const float*)d_in[7];
    const float* b_hh2 = (const float*)d_in[8];
    const float* lin_w = (const float*)d_in[9];
    const float* lin_b = (const float*)d_in[10];

    const int B = 2048;
    const int T = in_sizes[0] / B;   // 1024

    float* out = (float*)d_out;
    gru_seq_kernel<<<B / 2, 256, 0, stream>>>(input, w_ih1, w_hh1, b_ih1, b_hh1,
                                              w_ih2, w_hh2, b_ih2, b_hh2,
                                              lin_w, lin_b, out, T);
}